// Round 14
// baseline (415.270 us; speedup 1.0000x reference)
//
#include <hip/hip_runtime.h>
#include <hip/hip_bf16.h>
#include <cstdint>
#include <cstddef>

#define N_NODES 262144
#define NGRAPH  2048
#define DIM     512
#define HID3    1536
#define OUTD    128

typedef __attribute__((ext_vector_type(8))) short  short8;
typedef __attribute__((ext_vector_type(4))) float  floatx4;
typedef __attribute__((ext_vector_type(2))) float  floatx2;

__device__ inline unsigned short f2bf(float f) {
    union { float f; uint32_t u; } v; v.f = f;
    uint32_t u = v.u;
    return (unsigned short)((u + 0x7fffu + ((u >> 16) & 1u)) >> 16);
}
__device__ inline float bf2f(unsigned short h) {
    union { uint32_t u; float f; } v; v.u = ((uint32_t)h) << 16; return v.f;
}

__device__ __forceinline__ void gload_lds16(const void* g, void* l) {
    __builtin_amdgcn_global_load_lds((const __attribute__((address_space(1))) void*)g,
                                     (__attribute__((address_space(3))) void*)l, 16, 0, 0);
}

__device__ __forceinline__ int lbound(const int* __restrict__ seg, int b) {
    int lo = 0, hi = N_NODES;
    while (lo < hi) { int mid = (lo + hi) >> 1; if (seg[mid] < b) lo = mid + 1; else hi = mid; }
    return lo;
}

// ============ K1: init (sum-pool h0, left_att, x->fp8, starts) + weight prep ============
template<bool WRITE_XQ>
__global__ __launch_bounds__(256) void k_init(const float* __restrict__ x,
        const int* __restrict__ seg, const float* __restrict__ watl,
        const float* __restrict__ Wih, const float* __restrict__ Whh,
        const float* __restrict__ Wnode,
        float* __restrict__ left_att, float* __restrict__ hcur,
        unsigned short* __restrict__ hcur_bf, unsigned char* __restrict__ xq,
        unsigned short* __restrict__ Wihb, unsigned short* __restrict__ Whhb,
        unsigned short* __restrict__ WnT, int* __restrict__ starts) {
    int t = threadIdx.x;
    int bid = blockIdx.x;

    if (bid >= 3584) {            // ---- WnT transpose ----
        __shared__ float tile[32][33];
        int idx = bid - 3584;
        int bx = idx >> 4, by = idx & 15;
        int tx = t & 31, ty = t >> 5;
        #pragma unroll
        for (int r = 0; r < 32; r += 8)
            tile[ty + r][tx] = Wnode[(size_t)(bx * 32 + ty + r) * DIM + by * 32 + tx];
        __syncthreads();
        #pragma unroll
        for (int r = 0; r < 32; r += 8)
            WnT[(size_t)(by * 32 + ty + r) * DIM + bx * 32 + tx] = f2bf(tile[tx][ty + r]);
        return;
    }
    if (bid >= 2048) {            // ---- Wih/Whh converts ----
        int isW2 = bid >= 2816;
        int i4 = (bid - (isW2 ? 2816 : 2048)) * 256 + t;
        const float* src = isW2 ? Whh : Wih;
        unsigned short* dst = isW2 ? Whhb : Wihb;
        floatx4 a = *reinterpret_cast<const floatx4*>(src + (size_t)i4 * 4);
        ushort4 o;
        o.x = f2bf(a[0]); o.y = f2bf(a[1]); o.z = f2bf(a[2]); o.w = f2bf(a[3]);
        *reinterpret_cast<ushort4*>(dst + (size_t)i4 * 4) = o;
        return;
    }

    // ---- per-graph init ----
    __shared__ float wl[DIM];
    __shared__ float red[4 * DIM];
    int b = bid;
    wl[t] = watl[t]; wl[t + 256] = watl[t + 256];
    int s = lbound(seg, b), e = lbound(seg, b + 1);
    if (t == 0) {
        starts[b] = s;
        if (b == NGRAPH - 1) starts[NGRAPH] = e;
    }
    __syncthreads();
    int w = t >> 6, lane = t & 63;
    int f0 = lane * 4;
    float acc[8] = {0.f,0.f,0.f,0.f,0.f,0.f,0.f,0.f};

    auto proc = [&](int i, floatx4 v0, floatx4 v1) {
        acc[0] += v0[0]; acc[1] += v0[1]; acc[2] += v0[2]; acc[3] += v0[3];
        acc[4] += v1[0]; acc[5] += v1[1]; acc[6] += v1[2]; acc[7] += v1[3];
        float dot = v0[0]*wl[f0] + v0[1]*wl[f0+1] + v0[2]*wl[f0+2] + v0[3]*wl[f0+3]
                  + v1[0]*wl[256+f0] + v1[1]*wl[256+f0+1] + v1[2]*wl[256+f0+2] + v1[3]*wl[256+f0+3];
        #pragma unroll
        for (int off = 32; off > 0; off >>= 1) dot += __shfl_xor(dot, off);
        if (lane == 0) left_att[i] = dot;
        if constexpr (WRITE_XQ) {
            unsigned int q0 = (unsigned int)__builtin_amdgcn_cvt_pk_fp8_f32(v0[0], v0[1], 0, false);
            q0 = (unsigned int)__builtin_amdgcn_cvt_pk_fp8_f32(v0[2], v0[3], (int)q0, true);
            unsigned int q1 = (unsigned int)__builtin_amdgcn_cvt_pk_fp8_f32(v1[0], v1[1], 0, false);
            q1 = (unsigned int)__builtin_amdgcn_cvt_pk_fp8_f32(v1[2], v1[3], (int)q1, true);
            *reinterpret_cast<unsigned int*>(xq + (size_t)i * DIM + f0) = q0;
            *reinterpret_cast<unsigned int*>(xq + (size_t)i * DIM + 256 + f0) = q1;
        }
    };

    auto ld = [&](int i, int half) -> floatx4 {
        return __builtin_nontemporal_load(
            reinterpret_cast<const floatx4*>(x + (size_t)i * DIM + half * 256 + f0));
    };

    int i = s + w;
    for (; i + 12 < e; i += 16) {
        floatx4 a0 = ld(i, 0),      a1 = ld(i, 1);
        floatx4 b0 = ld(i + 4, 0),  b1 = ld(i + 4, 1);
        floatx4 c0 = ld(i + 8, 0),  c1 = ld(i + 8, 1);
        floatx4 d0 = ld(i + 12, 0), d1 = ld(i + 12, 1);
        proc(i, a0, a1);
        proc(i + 4, b0, b1);
        proc(i + 8, c0, c1);
        proc(i + 12, d0, d1);
    }
    for (; i < e; i += 4) {
        floatx4 a0 = ld(i, 0), a1 = ld(i, 1);
        proc(i, a0, a1);
    }

    #pragma unroll
    for (int j = 0; j < 4; j++) {
        red[w * DIM + f0 + j]       = acc[j];
        red[w * DIM + 256 + f0 + j] = acc[4 + j];
    }
    __syncthreads();
    float s0 = red[t]       + red[DIM + t]       + red[2*DIM + t]       + red[3*DIM + t];
    float s1 = red[256 + t] + red[DIM + 256 + t] + red[2*DIM + 256 + t] + red[3*DIM + 256 + t];
    hcur[(size_t)b * DIM + t] = s0;
    hcur[(size_t)b * DIM + 256 + t] = s1;
    hcur_bf[(size_t)b * DIM + t] = f2bf(s0);
    hcur_bf[(size_t)b * DIM + 256 + t] = f2bf(s1);
}

// ============ K2: attention (+ optional fused GRU gate prologue, bf16 gi/gh) ============
template<bool XQ, bool FUSE_GATE>
__global__ __launch_bounds__(256) void k_att(const float* __restrict__ x,
        const unsigned char* __restrict__ xq, const float* __restrict__ left,
        const int* __restrict__ starts, float* __restrict__ hcur,
        unsigned short* __restrict__ hcurbf,
        const unsigned short* __restrict__ gib, const unsigned short* __restrict__ ghb,
        const float* __restrict__ bih, const float* __restrict__ bhh,
        const float* __restrict__ watr, unsigned short* __restrict__ swbf) {
    __shared__ float red[4 * DIM];
    __shared__ float rsh[4], rsm[4], rscal[4];
    int b = blockIdx.x, t = threadIdx.x;
    int w = t >> 6, lane = t & 63;

    float p;
    if constexpr (FUSE_GATE) {
        size_t gb = (size_t)b * HID3;
        float o01[2];
        #pragma unroll
        for (int half = 0; half < 2; ++half) {
            int j = t + half * 256;
            float gir = bf2f(gib[gb + j])        + bih[j];
            float giz = bf2f(gib[gb + 512 + j])  + bih[512 + j];
            float gin = bf2f(gib[gb + 1024 + j]) + bih[1024 + j];
            float ghr = bf2f(ghb[gb + j])        + bhh[j];
            float ghz = bf2f(ghb[gb + 512 + j])  + bhh[512 + j];
            float ghn = bf2f(ghb[gb + 1024 + j]) + bhh[1024 + j];
            float rg = 1.0f / (1.0f + __expf(-(gir + ghr)));
            float zg = 1.0f / (1.0f + __expf(-(giz + ghz)));
            float nn = tanhf(gin + rg * ghn);
            float hp = hcur[(size_t)b * DIM + j];
            float nh = (1.0f - zg) * nn + zg * hp;
            float o = nh / (1.0f + __expf(-nh));
            hcur[(size_t)b * DIM + j] = o;
            hcurbf[(size_t)b * DIM + j] = f2bf(o);
            o01[half] = o;
        }
        p = o01[0] * watr[t] + o01[1] * watr[t + 256];
    } else {
        p = hcur[(size_t)b * DIM + t] * watr[t] + hcur[(size_t)b * DIM + 256 + t] * watr[256 + t];
    }
    #pragma unroll
    for (int off = 32; off > 0; off >>= 1) p += __shfl_xor(p, off);
    if (lane == 0) rsh[w] = p;
    int s = starts[b], e = starts[b + 1];
    __syncthreads();
    float ra = rsh[0] + rsh[1] + rsh[2] + rsh[3];

    float m = -1e30f;
    for (int i = s + t; i < e; i += 256) {
        float a = left[i] + ra; a = a >= 0.f ? a : 0.01f * a;
        m = fmaxf(m, a);
    }
    #pragma unroll
    for (int off = 32; off > 0; off >>= 1) m = fmaxf(m, __shfl_xor(m, off));
    if (lane == 0) rsm[w] = m;
    __syncthreads();
    m = fmaxf(fmaxf(rsm[0], rsm[1]), fmaxf(rsm[2], rsm[3]));

    float esum = 0.f;
    if constexpr (XQ) {
        int h  = lane >> 5;
        int fl = (lane & 31) * 16;
        float acc[16];
        #pragma unroll
        for (int j = 0; j < 16; j++) acc[j] = 0.f;
        const unsigned char* xrow = xq + fl;

        auto rowcalc = [&](uint4 q, float lv) {
            float a = lv + ra; a = a >= 0.f ? a : 0.01f * a;
            float e0 = __expf(a - m);
            esum += e0;
            floatx2 p0 = __builtin_amdgcn_cvt_pk_f32_fp8((int)q.x, false);
            floatx2 p1 = __builtin_amdgcn_cvt_pk_f32_fp8((int)q.x, true);
            floatx2 p2 = __builtin_amdgcn_cvt_pk_f32_fp8((int)q.y, false);
            floatx2 p3 = __builtin_amdgcn_cvt_pk_f32_fp8((int)q.y, true);
            floatx2 p4 = __builtin_amdgcn_cvt_pk_f32_fp8((int)q.z, false);
            floatx2 p5 = __builtin_amdgcn_cvt_pk_f32_fp8((int)q.z, true);
            floatx2 p6 = __builtin_amdgcn_cvt_pk_f32_fp8((int)q.w, false);
            floatx2 p7 = __builtin_amdgcn_cvt_pk_f32_fp8((int)q.w, true);
            acc[0]  += e0 * p0[0]; acc[1]  += e0 * p0[1];
            acc[2]  += e0 * p1[0]; acc[3]  += e0 * p1[1];
            acc[4]  += e0 * p2[0]; acc[5]  += e0 * p2[1];
            acc[6]  += e0 * p3[0]; acc[7]  += e0 * p3[1];
            acc[8]  += e0 * p4[0]; acc[9]  += e0 * p4[1];
            acc[10] += e0 * p5[0]; acc[11] += e0 * p5[1];
            acc[12] += e0 * p6[0]; acc[13] += e0 * p6[1];
            acc[14] += e0 * p7[0]; acc[15] += e0 * p7[1];
        };

        int base = s + 2 * w;
        for (; base + 26 <= e; base += 32) {
            int r0 = base + h, r1 = base + 8 + h, r2 = base + 16 + h, r3 = base + 24 + h;
            uint4 q0 = *reinterpret_cast<const uint4*>(xrow + (size_t)r0 * DIM);
            uint4 q1 = *reinterpret_cast<const uint4*>(xrow + (size_t)r1 * DIM);
            uint4 q2 = *reinterpret_cast<const uint4*>(xrow + (size_t)r2 * DIM);
            uint4 q3 = *reinterpret_cast<const uint4*>(xrow + (size_t)r3 * DIM);
            float l0 = left[r0], l1 = left[r1], l2 = left[r2], l3 = left[r3];
            rowcalc(q0, l0); rowcalc(q1, l1); rowcalc(q2, l2); rowcalc(q3, l3);
        }
        for (; base + 10 <= e; base += 16) {
            int r0 = base + h, r1 = base + 8 + h;
            uint4 q0 = *reinterpret_cast<const uint4*>(xrow + (size_t)r0 * DIM);
            uint4 q1 = *reinterpret_cast<const uint4*>(xrow + (size_t)r1 * DIM);
            float l0 = left[r0], l1 = left[r1];
            rowcalc(q0, l0); rowcalc(q1, l1);
        }
        for (; base < e; base += 8) {
            int r = base + h;
            if (r < e) {
                uint4 q = *reinterpret_cast<const uint4*>(xrow + (size_t)r * DIM);
                rowcalc(q, left[r]);
            }
        }
        #pragma unroll
        for (int j = 0; j < 16; j++) acc[j] += __shfl_xor(acc[j], 32);
        if (lane < 32) {
            #pragma unroll
            for (int j = 0; j < 16; j++) red[w * DIM + fl + j] = acc[j];
        }
    } else {
        int f0 = lane * 4;
        float acc[8] = {0.f,0.f,0.f,0.f,0.f,0.f,0.f,0.f};
        for (int i = s + w; i < e; i += 4) {
            float a0 = left[i] + ra; a0 = a0 >= 0.f ? a0 : 0.01f * a0;
            float e0 = __expf(a0 - m);
            esum += e0 * 32.0f;
            float4 v0 = *reinterpret_cast<const float4*>(x + (size_t)i * DIM + f0);
            float4 v1 = *reinterpret_cast<const float4*>(x + (size_t)i * DIM + 256 + f0);
            acc[0] += e0 * v0.x; acc[1] += e0 * v0.y; acc[2] += e0 * v0.z; acc[3] += e0 * v0.w;
            acc[4] += e0 * v1.x; acc[5] += e0 * v1.y; acc[6] += e0 * v1.z; acc[7] += e0 * v1.w;
        }
        #pragma unroll
        for (int j = 0; j < 4; j++) {
            red[w * DIM + f0 + j]       = acc[j];
            red[w * DIM + 256 + f0 + j] = acc[4 + j];
        }
    }
    #pragma unroll
    for (int off = 32; off > 0; off >>= 1) esum += __shfl_xor(esum, off);
    if (lane == 0) rscal[w] = esum;
    __syncthreads();
    float tot = (rscal[0] + rscal[1] + rscal[2] + rscal[3]) * (1.0f / 32.0f);
    float inv = tot > 0.f ? 1.0f / tot : 0.0f;
    float s0 = (red[t]       + red[DIM + t]       + red[2*DIM + t]       + red[3*DIM + t])       * inv;
    float s1 = (red[256 + t] + red[DIM + 256 + t] + red[2*DIM + 256 + t] + red[3*DIM + 256 + t]) * inv;
    swbf[(size_t)b * DIM + t] = f2bf(s0);
    swbf[(size_t)b * DIM + 256 + t] = f2bf(s1);
}

// ============ K3: bf16 MFMA GEMM, 2-phase pipeline, dual-problem z-select (R9 128-tile) ============
// mode: 1 = elu -> bf16, 2 = plain bf16
__global__ __launch_bounds__(256, 2) void k_gemm(const unsigned short* __restrict__ A0,
        const unsigned short* __restrict__ Wt0, unsigned short* __restrict__ C0,
        int mode0, int Ncols0,
        const unsigned short* __restrict__ A1, const unsigned short* __restrict__ Wt1,
        unsigned short* __restrict__ C1, int mode1, int Ncols1) {
    const int z = blockIdx.z;
    const unsigned short* A  = z ? A1  : A0;
    const unsigned short* Wt = z ? Wt1 : Wt0;
    unsigned short* C = z ? C1 : C0;
    const int mode  = z ? mode1 : mode0;
    const int Ncols = z ? Ncols1 : Ncols0;

    __shared__ __align__(16) unsigned short lA[2][128 * 64];
    __shared__ __align__(16) unsigned short lW[2][128 * 64];

    int t = threadIdx.x;
    int w = t >> 6, lane = t & 63;
    int wr = w >> 1, wc = w & 1;
    int mbase = blockIdx.x * 128;
    int nbase = blockIdx.y * 128;
    int fr = lane & 15, hi = lane >> 4;
    int swz_r = (fr & 7) << 4;

    int rbase = t >> 3;
    int cole = ((((t & 7) * 16) ^ ((rbase & 7) << 4)) >> 1);
    int ldsoff = t * 16;

    floatx4 acc[4][4];
    #pragma unroll
    for (int m = 0; m < 4; m++)
        #pragma unroll
        for (int n = 0; n < 4; n++) {
            acc[m][n][0] = 0.f; acc[m][n][1] = 0.f; acc[m][n][2] = 0.f; acc[m][n][3] = 0.f;
        }

    const unsigned short* gA = A  + (size_t)(mbase + rbase) * DIM + cole;
    const unsigned short* gW = Wt + (size_t)(nbase + rbase) * DIM + cole;

    auto stage = [&](int kk, int buf) {
        #pragma unroll
        for (int c = 0; c < 4; ++c) {
            gload_lds16(gA + (size_t)(c * 32) * DIM + kk, (char*)&lA[buf][0] + c * 4096 + ldsoff);
            gload_lds16(gW + (size_t)(c * 32) * DIM + kk, (char*)&lW[buf][0] + c * 4096 + ldsoff);
        }
    };

    stage(0, 0);
    __syncthreads();
    int cur = 0;
    for (int it = 0; it < 8; ++it) {
        if (it < 7) stage((it + 1) * 64, cur ^ 1);
        #pragma unroll
        for (int ks = 0; ks < 2; ++ks) {
            short8 af[4], bf[4];
            int bc = (ks * 64 + hi * 16) ^ swz_r;
            #pragma unroll
            for (int m = 0; m < 4; ++m) {
                int row = wr * 64 + m * 16 + fr;
                af[m] = *reinterpret_cast<const short8*>(&lA[cur][(row * 128 + bc) >> 1]);
            }
            #pragma unroll
            for (int n = 0; n < 4; ++n) {
                int row = wc * 64 + n * 16 + fr;
                bf[n] = *reinterpret_cast<const short8*>(&lW[cur][(row * 128 + bc) >> 1]);
            }
            #pragma unroll
            for (int m = 0; m < 4; ++m)
                #pragma unroll
                for (int n = 0; n < 4; ++n)
                    acc[m][n] = __builtin_amdgcn_mfma_f32_16x16x32_bf16(af[m], bf[n], acc[m][n], 0, 0, 0);
        }
        if (it < 7) __syncthreads();
        cur ^= 1;
    }

    int rq = hi * 4;
    #pragma unroll
    for (int m = 0; m < 4; m++) {
        #pragma unroll
        for (int n = 0; n < 4; n++) {
            int col = nbase + wc * 64 + n * 16 + fr;
            #pragma unroll
            for (int r = 0; r < 4; r++) {
                int row = mbase + wr * 64 + m * 16 + rq + r;
                float v = acc[m][n][r];
                if (mode == 1) v = v > 0.f ? v : (__expf(v) - 1.0f);
                C[(size_t)row * Ncols + col] = f2bf(v);
            }
        }
    }
}

// ============ K4: final linear with fused GRU gate (ts1, bf16 gi/gh) ============
__global__ __launch_bounds__(128) void k_fin(const float* __restrict__ hcur,
        const unsigned short* __restrict__ gib, const unsigned short* __restrict__ ghb,
        const float* __restrict__ bih, const float* __restrict__ bhh,
        const float* __restrict__ Wlin, const float* __restrict__ blin,
        float* __restrict__ out) {
    __shared__ float rows[16 * DIM];
    int t = threadIdx.x;
    int b0 = blockIdx.x * 16;
    for (int k = 0; k < 16; ++k) {
        int i4 = t + k * 128;
        int bl = i4 >> 7;
        int j  = (i4 & 127) << 2;
        size_t gb = (size_t)(b0 + bl) * HID3;
        ushort4 gir4 = *reinterpret_cast<const ushort4*>(gib + gb + j);
        ushort4 giz4 = *reinterpret_cast<const ushort4*>(gib + gb + 512 + j);
        ushort4 gin4 = *reinterpret_cast<const ushort4*>(gib + gb + 1024 + j);
        ushort4 ghr4 = *reinterpret_cast<const ushort4*>(ghb + gb + j);
        ushort4 ghz4 = *reinterpret_cast<const ushort4*>(ghb + gb + 512 + j);
        ushort4 ghn4 = *reinterpret_cast<const ushort4*>(ghb + gb + 1024 + j);
        floatx4 bir = *reinterpret_cast<const floatx4*>(bih + j);
        floatx4 biz = *reinterpret_cast<const floatx4*>(bih + 512 + j);
        floatx4 bin = *reinterpret_cast<const floatx4*>(bih + 1024 + j);
        floatx4 bhr = *reinterpret_cast<const floatx4*>(bhh + j);
        floatx4 bhz = *reinterpret_cast<const floatx4*>(bhh + 512 + j);
        floatx4 bhn = *reinterpret_cast<const floatx4*>(bhh + 1024 + j);
        floatx4 hp  = *reinterpret_cast<const floatx4*>(hcur + (size_t)(b0 + bl) * DIM + j);
        floatx4 ov;
        const unsigned short* girp = &gir4.x;
        const unsigned short* gizp = &giz4.x;
        const unsigned short* ginp = &gin4.x;
        const unsigned short* ghrp = &ghr4.x;
        const unsigned short* ghzp = &ghz4.x;
        const unsigned short* ghnp = &ghn4.x;
        #pragma unroll
        for (int r = 0; r < 4; r++) {
            float rg = 1.0f / (1.0f + __expf(-(bf2f(girp[r]) + bir[r] + bf2f(ghrp[r]) + bhr[r])));
            float zg = 1.0f / (1.0f + __expf(-(bf2f(gizp[r]) + biz[r] + bf2f(ghzp[r]) + bhz[r])));
            float nn = tanhf(bf2f(ginp[r]) + bin[r] + rg * (bf2f(ghnp[r]) + bhn[r]));
            float nh = (1.0f - zg) * nn + zg * hp[r];
            ov[r] = nh / (1.0f + __expf(-nh));
        }
        *reinterpret_cast<floatx4*>(rows + (size_t)i4 * 4) = ov;
    }
    __syncthreads();
    float acc[16];
    #pragma unroll
    for (int r = 0; r < 16; r++) acc[r] = 0.f;
    #pragma unroll 4
    for (int k = 0; k < DIM; k++) {
        float wv = Wlin[k * OUTD + t];
        #pragma unroll
        for (int r = 0; r < 16; r++) acc[r] += rows[r * DIM + k] * wv;
    }
    float bl = blin[t];
    #pragma unroll
    for (int r = 0; r < 16; r++) out[(size_t)(b0 + r) * OUTD + t] = acc[r] + bl;
}

extern "C" void kernel_launch(void* const* d_in, const int* in_sizes, int n_in,
                              void* d_out, int out_size, void* d_ws, size_t ws_size,
                              hipStream_t stream) {
    const float* x     = (const float*)d_in[0];
    const int*   seg   = (const int*)d_in[1];
    const float* watl  = (const float*)d_in[2];
    const float* watr  = (const float*)d_in[3];
    const float* Wnode = (const float*)d_in[4];
    const float* Wih   = (const float*)d_in[5];
    const float* Whh   = (const float*)d_in[6];
    const float* bih   = (const float*)d_in[7];
    const float* bhh   = (const float*)d_in[8];
    const float* Wlin  = (const float*)d_in[9];
    const float* blin  = (const float*)d_in[10];
    float* out = (float*)d_out;

    char* ws = (char*)d_ws;
    size_t off = 0;
    auto alloc = [&](size_t bytes) -> void* {
        void* p = ws + off;
        off += bytes;
        off = (off + 255) & ~(size_t)255;
        return p;
    };
    float*          left    = (float*)          alloc((size_t)N_NODES * sizeof(float));
    float*          hcur    = (float*)          alloc((size_t)NGRAPH * DIM * sizeof(float));
    unsigned short* hcurbf  = (unsigned short*) alloc((size_t)NGRAPH * DIM * 2);
    unsigned short* hgbf    = (unsigned short*) alloc((size_t)NGRAPH * DIM * 2);
    unsigned short* swbf    = (unsigned short*) alloc((size_t)NGRAPH * DIM * 2);
    unsigned short* gib     = (unsigned short*) alloc((size_t)NGRAPH * HID3 * 2);
    unsigned short* ghb     = (unsigned short*) alloc((size_t)NGRAPH * HID3 * 2);
    unsigned short* WnT     = (unsigned short*) alloc((size_t)DIM * DIM * 2);
    unsigned short* Wihb    = (unsigned short*) alloc((size_t)HID3 * DIM * 2);
    unsigned short* Whhb    = (unsigned short*) alloc((size_t)HID3 * DIM * 2);
    int*            starts  = (int*)            alloc((NGRAPH + 1) * sizeof(int));
    unsigned char*  xq      = (unsigned char*)(ws + off);
    bool use_xq = (off + (size_t)N_NODES * DIM) <= ws_size;

    if (use_xq)
        k_init<true ><<<3840, 256, 0, stream>>>(x, seg, watl, Wih, Whh, Wnode,
                left, hcur, hcurbf, xq, Wihb, Whhb, WnT, starts);
    else
        k_init<false><<<3840, 256, 0, stream>>>(x, seg, watl, Wih, Whh, Wnode,
                left, hcur, hcurbf, nullptr, Wihb, Whhb, WnT, starts);

    for (int ts = 0; ts < 2; ts++) {
        if (use_xq) {
            if (ts == 0)
                k_att<true , false><<<NGRAPH, 256, 0, stream>>>(x, xq, left, starts,
                        hcur, hcurbf, gib, ghb, bih, bhh, watr, swbf);
            else
                k_att<true , true ><<<NGRAPH, 256, 0, stream>>>(x, xq, left, starts,
                        hcur, hcurbf, gib, ghb, bih, bhh, watr, swbf);
        } else {
            if (ts == 0)
                k_att<false, false><<<NGRAPH, 256, 0, stream>>>(x, xq, left, starts,
                        hcur, hcurbf, gib, ghb, bih, bhh, watr, swbf);
            else
                k_att<false, true ><<<NGRAPH, 256, 0, stream>>>(x, xq, left, starts,
                        hcur, hcurbf, gib, ghb, bih, bhh, watr, swbf);
        }
        // DIAGNOSTIC: A and C each launched 4x (idempotent).
        // (dur - 292.9) / 6 = t(A) + t(C) per pair.
        for (int rep = 0; rep < 4; ++rep)
            k_gemm<<<dim3(NGRAPH / 128, DIM / 128, 1), 256, 0, stream>>>(
                swbf, WnT, hgbf, 1, DIM,
                nullptr, nullptr, nullptr, 0, 0);
        for (int rep = 0; rep < 4; ++rep)
            k_gemm<<<dim3(NGRAPH / 128, HID3 / 128, 2), 256, 0, stream>>>(
                hgbf, Wihb, gib, 2, HID3,
                hcurbf, Whhb, ghb, 2, HID3);
    }
    k_fin<<<NGRAPH / 16, 128, 0, stream>>>(hcur, gib, ghb, bih, bhh, Wlin, blin, out);
}

// Round 15
// 335.774 us; speedup vs baseline: 1.2368x; 1.2368x over previous
//
#include <hip/hip_runtime.h>
#include <hip/hip_bf16.h>
#include <cstdint>
#include <cstddef>

#define N_NODES 262144
#define NGRAPH  2048
#define DIM     512
#define HID3    1536
#define OUTD    128

typedef __attribute__((ext_vector_type(8))) short  short8;
typedef __attribute__((ext_vector_type(4))) float  floatx4;
typedef __attribute__((ext_vector_type(2))) float  floatx2;

__device__ inline unsigned short f2bf(float f) {
    union { float f; uint32_t u; } v; v.f = f;
    uint32_t u = v.u;
    return (unsigned short)((u + 0x7fffu + ((u >> 16) & 1u)) >> 16);
}
__device__ inline float bf2f(unsigned short h) {
    union { uint32_t u; float f; } v; v.u = ((uint32_t)h) << 16; return v.f;
}

__device__ __forceinline__ void gload_lds16(const void* g, void* l) {
    __builtin_amdgcn_global_load_lds((const __attribute__((address_space(1))) void*)g,
                                     (__attribute__((address_space(3))) void*)l, 16, 0, 0);
}

__device__ __forceinline__ int lbound(const int* __restrict__ seg, int b) {
    int lo = 0, hi = N_NODES;
    while (lo < hi) { int mid = (lo + hi) >> 1; if (seg[mid] < b) lo = mid + 1; else hi = mid; }
    return lo;
}

// ============ K1: init (sum-pool h0, left_att, x->fp8, starts) + weight prep ============
// A/B this round: x loaded with PLAIN loads (nt hint removed) — sole change vs R9 baseline.
template<bool WRITE_XQ>
__global__ __launch_bounds__(256) void k_init(const float* __restrict__ x,
        const int* __restrict__ seg, const float* __restrict__ watl,
        const float* __restrict__ Wih, const float* __restrict__ Whh,
        const float* __restrict__ Wnode,
        float* __restrict__ left_att, float* __restrict__ hcur,
        unsigned short* __restrict__ hcur_bf, unsigned char* __restrict__ xq,
        unsigned short* __restrict__ Wihb, unsigned short* __restrict__ Whhb,
        unsigned short* __restrict__ WnT, int* __restrict__ starts) {
    int t = threadIdx.x;
    int bid = blockIdx.x;

    if (bid >= 3584) {            // ---- WnT transpose ----
        __shared__ float tile[32][33];
        int idx = bid - 3584;
        int bx = idx >> 4, by = idx & 15;
        int tx = t & 31, ty = t >> 5;
        #pragma unroll
        for (int r = 0; r < 32; r += 8)
            tile[ty + r][tx] = Wnode[(size_t)(bx * 32 + ty + r) * DIM + by * 32 + tx];
        __syncthreads();
        #pragma unroll
        for (int r = 0; r < 32; r += 8)
            WnT[(size_t)(by * 32 + ty + r) * DIM + bx * 32 + tx] = f2bf(tile[tx][ty + r]);
        return;
    }
    if (bid >= 2048) {            // ---- Wih/Whh converts ----
        int isW2 = bid >= 2816;
        int i4 = (bid - (isW2 ? 2816 : 2048)) * 256 + t;
        const float* src = isW2 ? Whh : Wih;
        unsigned short* dst = isW2 ? Whhb : Wihb;
        floatx4 a = *reinterpret_cast<const floatx4*>(src + (size_t)i4 * 4);
        ushort4 o;
        o.x = f2bf(a[0]); o.y = f2bf(a[1]); o.z = f2bf(a[2]); o.w = f2bf(a[3]);
        *reinterpret_cast<ushort4*>(dst + (size_t)i4 * 4) = o;
        return;
    }

    // ---- per-graph init ----
    __shared__ float wl[DIM];
    __shared__ float red[4 * DIM];
    int b = bid;
    wl[t] = watl[t]; wl[t + 256] = watl[t + 256];
    int s = lbound(seg, b), e = lbound(seg, b + 1);
    if (t == 0) {
        starts[b] = s;
        if (b == NGRAPH - 1) starts[NGRAPH] = e;
    }
    __syncthreads();
    int w = t >> 6, lane = t & 63;
    int f0 = lane * 4;
    float acc[8] = {0.f,0.f,0.f,0.f,0.f,0.f,0.f,0.f};

    auto proc = [&](int i, floatx4 v0, floatx4 v1) {
        acc[0] += v0[0]; acc[1] += v0[1]; acc[2] += v0[2]; acc[3] += v0[3];
        acc[4] += v1[0]; acc[5] += v1[1]; acc[6] += v1[2]; acc[7] += v1[3];
        float dot = v0[0]*wl[f0] + v0[1]*wl[f0+1] + v0[2]*wl[f0+2] + v0[3]*wl[f0+3]
                  + v1[0]*wl[256+f0] + v1[1]*wl[256+f0+1] + v1[2]*wl[256+f0+2] + v1[3]*wl[256+f0+3];
        #pragma unroll
        for (int off = 32; off > 0; off >>= 1) dot += __shfl_xor(dot, off);
        if (lane == 0) left_att[i] = dot;
        if constexpr (WRITE_XQ) {
            unsigned int q0 = (unsigned int)__builtin_amdgcn_cvt_pk_fp8_f32(v0[0], v0[1], 0, false);
            q0 = (unsigned int)__builtin_amdgcn_cvt_pk_fp8_f32(v0[2], v0[3], (int)q0, true);
            unsigned int q1 = (unsigned int)__builtin_amdgcn_cvt_pk_fp8_f32(v1[0], v1[1], 0, false);
            q1 = (unsigned int)__builtin_amdgcn_cvt_pk_fp8_f32(v1[2], v1[3], (int)q1, true);
            *reinterpret_cast<unsigned int*>(xq + (size_t)i * DIM + f0) = q0;
            *reinterpret_cast<unsigned int*>(xq + (size_t)i * DIM + 256 + f0) = q1;
        }
    };

    auto ld = [&](int i, int half) -> floatx4 {
        return *reinterpret_cast<const floatx4*>(x + (size_t)i * DIM + half * 256 + f0);
    };

    int i = s + w;
    for (; i + 12 < e; i += 16) {
        floatx4 a0 = ld(i, 0),      a1 = ld(i, 1);
        floatx4 b0 = ld(i + 4, 0),  b1 = ld(i + 4, 1);
        floatx4 c0 = ld(i + 8, 0),  c1 = ld(i + 8, 1);
        floatx4 d0 = ld(i + 12, 0), d1 = ld(i + 12, 1);
        proc(i, a0, a1);
        proc(i + 4, b0, b1);
        proc(i + 8, c0, c1);
        proc(i + 12, d0, d1);
    }
    for (; i < e; i += 4) {
        floatx4 a0 = ld(i, 0), a1 = ld(i, 1);
        proc(i, a0, a1);
    }

    #pragma unroll
    for (int j = 0; j < 4; j++) {
        red[w * DIM + f0 + j]       = acc[j];
        red[w * DIM + 256 + f0 + j] = acc[4 + j];
    }
    __syncthreads();
    float s0 = red[t]       + red[DIM + t]       + red[2*DIM + t]       + red[3*DIM + t];
    float s1 = red[256 + t] + red[DIM + 256 + t] + red[2*DIM + 256 + t] + red[3*DIM + 256 + t];
    hcur[(size_t)b * DIM + t] = s0;
    hcur[(size_t)b * DIM + 256 + t] = s1;
    hcur_bf[(size_t)b * DIM + t] = f2bf(s0);
    hcur_bf[(size_t)b * DIM + 256 + t] = f2bf(s1);
}

// ============ K2: attention (+ optional fused GRU gate prologue, bf16 gi/gh) ============
template<bool XQ, bool FUSE_GATE>
__global__ __launch_bounds__(256) void k_att(const float* __restrict__ x,
        const unsigned char* __restrict__ xq, const float* __restrict__ left,
        const int* __restrict__ starts, float* __restrict__ hcur,
        unsigned short* __restrict__ hcurbf,
        const unsigned short* __restrict__ gib, const unsigned short* __restrict__ ghb,
        const float* __restrict__ bih, const float* __restrict__ bhh,
        const float* __restrict__ watr, unsigned short* __restrict__ swbf) {
    __shared__ float red[4 * DIM];
    __shared__ float rsh[4], rsm[4], rscal[4];
    int b = blockIdx.x, t = threadIdx.x;
    int w = t >> 6, lane = t & 63;

    float p;
    if constexpr (FUSE_GATE) {
        size_t gb = (size_t)b * HID3;
        float o01[2];
        #pragma unroll
        for (int half = 0; half < 2; ++half) {
            int j = t + half * 256;
            float gir = bf2f(gib[gb + j])        + bih[j];
            float giz = bf2f(gib[gb + 512 + j])  + bih[512 + j];
            float gin = bf2f(gib[gb + 1024 + j]) + bih[1024 + j];
            float ghr = bf2f(ghb[gb + j])        + bhh[j];
            float ghz = bf2f(ghb[gb + 512 + j])  + bhh[512 + j];
            float ghn = bf2f(ghb[gb + 1024 + j]) + bhh[1024 + j];
            float rg = 1.0f / (1.0f + __expf(-(gir + ghr)));
            float zg = 1.0f / (1.0f + __expf(-(giz + ghz)));
            float nn = tanhf(gin + rg * ghn);
            float hp = hcur[(size_t)b * DIM + j];
            float nh = (1.0f - zg) * nn + zg * hp;
            float o = nh / (1.0f + __expf(-nh));
            hcur[(size_t)b * DIM + j] = o;
            hcurbf[(size_t)b * DIM + j] = f2bf(o);
            o01[half] = o;
        }
        p = o01[0] * watr[t] + o01[1] * watr[t + 256];
    } else {
        p = hcur[(size_t)b * DIM + t] * watr[t] + hcur[(size_t)b * DIM + 256 + t] * watr[256 + t];
    }
    #pragma unroll
    for (int off = 32; off > 0; off >>= 1) p += __shfl_xor(p, off);
    if (lane == 0) rsh[w] = p;
    int s = starts[b], e = starts[b + 1];
    __syncthreads();
    float ra = rsh[0] + rsh[1] + rsh[2] + rsh[3];

    float m = -1e30f;
    for (int i = s + t; i < e; i += 256) {
        float a = left[i] + ra; a = a >= 0.f ? a : 0.01f * a;
        m = fmaxf(m, a);
    }
    #pragma unroll
    for (int off = 32; off > 0; off >>= 1) m = fmaxf(m, __shfl_xor(m, off));
    if (lane == 0) rsm[w] = m;
    __syncthreads();
    m = fmaxf(fmaxf(rsm[0], rsm[1]), fmaxf(rsm[2], rsm[3]));

    float esum = 0.f;
    if constexpr (XQ) {
        int h  = lane >> 5;
        int fl = (lane & 31) * 16;
        float acc[16];
        #pragma unroll
        for (int j = 0; j < 16; j++) acc[j] = 0.f;
        const unsigned char* xrow = xq + fl;

        auto rowcalc = [&](uint4 q, float lv) {
            float a = lv + ra; a = a >= 0.f ? a : 0.01f * a;
            float e0 = __expf(a - m);
            esum += e0;
            floatx2 p0 = __builtin_amdgcn_cvt_pk_f32_fp8((int)q.x, false);
            floatx2 p1 = __builtin_amdgcn_cvt_pk_f32_fp8((int)q.x, true);
            floatx2 p2 = __builtin_amdgcn_cvt_pk_f32_fp8((int)q.y, false);
            floatx2 p3 = __builtin_amdgcn_cvt_pk_f32_fp8((int)q.y, true);
            floatx2 p4 = __builtin_amdgcn_cvt_pk_f32_fp8((int)q.z, false);
            floatx2 p5 = __builtin_amdgcn_cvt_pk_f32_fp8((int)q.z, true);
            floatx2 p6 = __builtin_amdgcn_cvt_pk_f32_fp8((int)q.w, false);
            floatx2 p7 = __builtin_amdgcn_cvt_pk_f32_fp8((int)q.w, true);
            acc[0]  += e0 * p0[0]; acc[1]  += e0 * p0[1];
            acc[2]  += e0 * p1[0]; acc[3]  += e0 * p1[1];
            acc[4]  += e0 * p2[0]; acc[5]  += e0 * p2[1];
            acc[6]  += e0 * p3[0]; acc[7]  += e0 * p3[1];
            acc[8]  += e0 * p4[0]; acc[9]  += e0 * p4[1];
            acc[10] += e0 * p5[0]; acc[11] += e0 * p5[1];
            acc[12] += e0 * p6[0]; acc[13] += e0 * p6[1];
            acc[14] += e0 * p7[0]; acc[15] += e0 * p7[1];
        };

        int base = s + 2 * w;
        for (; base + 26 <= e; base += 32) {
            int r0 = base + h, r1 = base + 8 + h, r2 = base + 16 + h, r3 = base + 24 + h;
            uint4 q0 = *reinterpret_cast<const uint4*>(xrow + (size_t)r0 * DIM);
            uint4 q1 = *reinterpret_cast<const uint4*>(xrow + (size_t)r1 * DIM);
            uint4 q2 = *reinterpret_cast<const uint4*>(xrow + (size_t)r2 * DIM);
            uint4 q3 = *reinterpret_cast<const uint4*>(xrow + (size_t)r3 * DIM);
            float l0 = left[r0], l1 = left[r1], l2 = left[r2], l3 = left[r3];
            rowcalc(q0, l0); rowcalc(q1, l1); rowcalc(q2, l2); rowcalc(q3, l3);
        }
        for (; base + 10 <= e; base += 16) {
            int r0 = base + h, r1 = base + 8 + h;
            uint4 q0 = *reinterpret_cast<const uint4*>(xrow + (size_t)r0 * DIM);
            uint4 q1 = *reinterpret_cast<const uint4*>(xrow + (size_t)r1 * DIM);
            float l0 = left[r0], l1 = left[r1];
            rowcalc(q0, l0); rowcalc(q1, l1);
        }
        for (; base < e; base += 8) {
            int r = base + h;
            if (r < e) {
                uint4 q = *reinterpret_cast<const uint4*>(xrow + (size_t)r * DIM);
                rowcalc(q, left[r]);
            }
        }
        #pragma unroll
        for (int j = 0; j < 16; j++) acc[j] += __shfl_xor(acc[j], 32);
        if (lane < 32) {
            #pragma unroll
            for (int j = 0; j < 16; j++) red[w * DIM + fl + j] = acc[j];
        }
    } else {
        int f0 = lane * 4;
        float acc[8] = {0.f,0.f,0.f,0.f,0.f,0.f,0.f,0.f};
        for (int i = s + w; i < e; i += 4) {
            float a0 = left[i] + ra; a0 = a0 >= 0.f ? a0 : 0.01f * a0;
            float e0 = __expf(a0 - m);
            esum += e0 * 32.0f;
            float4 v0 = *reinterpret_cast<const float4*>(x + (size_t)i * DIM + f0);
            float4 v1 = *reinterpret_cast<const float4*>(x + (size_t)i * DIM + 256 + f0);
            acc[0] += e0 * v0.x; acc[1] += e0 * v0.y; acc[2] += e0 * v0.z; acc[3] += e0 * v0.w;
            acc[4] += e0 * v1.x; acc[5] += e0 * v1.y; acc[6] += e0 * v1.z; acc[7] += e0 * v1.w;
        }
        #pragma unroll
        for (int j = 0; j < 4; j++) {
            red[w * DIM + f0 + j]       = acc[j];
            red[w * DIM + 256 + f0 + j] = acc[4 + j];
        }
    }
    #pragma unroll
    for (int off = 32; off > 0; off >>= 1) esum += __shfl_xor(esum, off);
    if (lane == 0) rscal[w] = esum;
    __syncthreads();
    float tot = (rscal[0] + rscal[1] + rscal[2] + rscal[3]) * (1.0f / 32.0f);
    float inv = tot > 0.f ? 1.0f / tot : 0.0f;
    float s0 = (red[t]       + red[DIM + t]       + red[2*DIM + t]       + red[3*DIM + t])       * inv;
    float s1 = (red[256 + t] + red[DIM + 256 + t] + red[2*DIM + 256 + t] + red[3*DIM + 256 + t]) * inv;
    swbf[(size_t)b * DIM + t] = f2bf(s0);
    swbf[(size_t)b * DIM + 256 + t] = f2bf(s1);
}

// ============ K3: bf16 MFMA GEMM, 2-phase pipeline, dual-problem z-select ============
// mode: 1 = elu -> bf16, 2 = plain bf16
__global__ __launch_bounds__(256, 2) void k_gemm(const unsigned short* __restrict__ A0,
        const unsigned short* __restrict__ Wt0, unsigned short* __restrict__ C0,
        int mode0, int Ncols0,
        const unsigned short* __restrict__ A1, const unsigned short* __restrict__ Wt1,
        unsigned short* __restrict__ C1, int mode1, int Ncols1) {
    const int z = blockIdx.z;
    const unsigned short* A  = z ? A1  : A0;
    const unsigned short* Wt = z ? Wt1 : Wt0;
    unsigned short* C = z ? C1 : C0;
    const int mode  = z ? mode1 : mode0;
    const int Ncols = z ? Ncols1 : Ncols0;

    __shared__ __align__(16) unsigned short lA[2][128 * 64];
    __shared__ __align__(16) unsigned short lW[2][128 * 64];

    int t = threadIdx.x;
    int w = t >> 6, lane = t & 63;
    int wr = w >> 1, wc = w & 1;
    int mbase = blockIdx.x * 128;
    int nbase = blockIdx.y * 128;
    int fr = lane & 15, hi = lane >> 4;
    int swz_r = (fr & 7) << 4;

    int rbase = t >> 3;
    int cole = ((((t & 7) * 16) ^ ((rbase & 7) << 4)) >> 1);
    int ldsoff = t * 16;

    floatx4 acc[4][4];
    #pragma unroll
    for (int m = 0; m < 4; m++)
        #pragma unroll
        for (int n = 0; n < 4; n++) {
            acc[m][n][0] = 0.f; acc[m][n][1] = 0.f; acc[m][n][2] = 0.f; acc[m][n][3] = 0.f;
        }

    const unsigned short* gA = A  + (size_t)(mbase + rbase) * DIM + cole;
    const unsigned short* gW = Wt + (size_t)(nbase + rbase) * DIM + cole;

    auto stage = [&](int kk, int buf) {
        #pragma unroll
        for (int c = 0; c < 4; ++c) {
            gload_lds16(gA + (size_t)(c * 32) * DIM + kk, (char*)&lA[buf][0] + c * 4096 + ldsoff);
            gload_lds16(gW + (size_t)(c * 32) * DIM + kk, (char*)&lW[buf][0] + c * 4096 + ldsoff);
        }
    };

    stage(0, 0);
    __syncthreads();
    int cur = 0;
    for (int it = 0; it < 8; ++it) {
        if (it < 7) stage((it + 1) * 64, cur ^ 1);
        #pragma unroll
        for (int ks = 0; ks < 2; ++ks) {
            short8 af[4], bf[4];
            int bc = (ks * 64 + hi * 16) ^ swz_r;
            #pragma unroll
            for (int m = 0; m < 4; ++m) {
                int row = wr * 64 + m * 16 + fr;
                af[m] = *reinterpret_cast<const short8*>(&lA[cur][(row * 128 + bc) >> 1]);
            }
            #pragma unroll
            for (int n = 0; n < 4; ++n) {
                int row = wc * 64 + n * 16 + fr;
                bf[n] = *reinterpret_cast<const short8*>(&lW[cur][(row * 128 + bc) >> 1]);
            }
            #pragma unroll
            for (int m = 0; m < 4; ++m)
                #pragma unroll
                for (int n = 0; n < 4; ++n)
                    acc[m][n] = __builtin_amdgcn_mfma_f32_16x16x32_bf16(af[m], bf[n], acc[m][n], 0, 0, 0);
        }
        if (it < 7) __syncthreads();
        cur ^= 1;
    }

    int rq = hi * 4;
    #pragma unroll
    for (int m = 0; m < 4; m++) {
        #pragma unroll
        for (int n = 0; n < 4; n++) {
            int col = nbase + wc * 64 + n * 16 + fr;
            #pragma unroll
            for (int r = 0; r < 4; r++) {
                int row = mbase + wr * 64 + m * 16 + rq + r;
                float v = acc[m][n][r];
                if (mode == 1) v = v > 0.f ? v : (__expf(v) - 1.0f);
                C[(size_t)row * Ncols + col] = f2bf(v);
            }
        }
    }
}

// ============ K4: final linear with fused GRU gate (ts1, bf16 gi/gh) ============
__global__ __launch_bounds__(128) void k_fin(const float* __restrict__ hcur,
        const unsigned short* __restrict__ gib, const unsigned short* __restrict__ ghb,
        const float* __restrict__ bih, const float* __restrict__ bhh,
        const float* __restrict__ Wlin, const float* __restrict__ blin,
        float* __restrict__ out) {
    __shared__ float rows[16 * DIM];
    int t = threadIdx.x;
    int b0 = blockIdx.x * 16;
    for (int k = 0; k < 16; ++k) {
        int i4 = t + k * 128;
        int bl = i4 >> 7;
        int j  = (i4 & 127) << 2;
        size_t gb = (size_t)(b0 + bl) * HID3;
        ushort4 gir4 = *reinterpret_cast<const ushort4*>(gib + gb + j);
        ushort4 giz4 = *reinterpret_cast<const ushort4*>(gib + gb + 512 + j);
        ushort4 gin4 = *reinterpret_cast<const ushort4*>(gib + gb + 1024 + j);
        ushort4 ghr4 = *reinterpret_cast<const ushort4*>(ghb + gb + j);
        ushort4 ghz4 = *reinterpret_cast<const ushort4*>(ghb + gb + 512 + j);
        ushort4 ghn4 = *reinterpret_cast<const ushort4*>(ghb + gb + 1024 + j);
        floatx4 bir = *reinterpret_cast<const floatx4*>(bih + j);
        floatx4 biz = *reinterpret_cast<const floatx4*>(bih + 512 + j);
        floatx4 bin = *reinterpret_cast<const floatx4*>(bih + 1024 + j);
        floatx4 bhr = *reinterpret_cast<const floatx4*>(bhh + j);
        floatx4 bhz = *reinterpret_cast<const floatx4*>(bhh + 512 + j);
        floatx4 bhn = *reinterpret_cast<const floatx4*>(bhh + 1024 + j);
        floatx4 hp  = *reinterpret_cast<const floatx4*>(hcur + (size_t)(b0 + bl) * DIM + j);
        floatx4 ov;
        const unsigned short* girp = &gir4.x;
        const unsigned short* gizp = &giz4.x;
        const unsigned short* ginp = &gin4.x;
        const unsigned short* ghrp = &ghr4.x;
        const unsigned short* ghzp = &ghz4.x;
        const unsigned short* ghnp = &ghn4.x;
        #pragma unroll
        for (int r = 0; r < 4; r++) {
            float rg = 1.0f / (1.0f + __expf(-(bf2f(girp[r]) + bir[r] + bf2f(ghrp[r]) + bhr[r])));
            float zg = 1.0f / (1.0f + __expf(-(bf2f(gizp[r]) + biz[r] + bf2f(ghzp[r]) + bhz[r])));
            float nn = tanhf(bf2f(ginp[r]) + bin[r] + rg * (bf2f(ghnp[r]) + bhn[r]));
            float nh = (1.0f - zg) * nn + zg * hp[r];
            ov[r] = nh / (1.0f + __expf(-nh));
        }
        *reinterpret_cast<floatx4*>(rows + (size_t)i4 * 4) = ov;
    }
    __syncthreads();
    float acc[16];
    #pragma unroll
    for (int r = 0; r < 16; r++) acc[r] = 0.f;
    #pragma unroll 4
    for (int k = 0; k < DIM; k++) {
        float wv = Wlin[k * OUTD + t];
        #pragma unroll
        for (int r = 0; r < 16; r++) acc[r] += rows[r * DIM + k] * wv;
    }
    float bl = blin[t];
    #pragma unroll
    for (int r = 0; r < 16; r++) out[(size_t)(b0 + r) * OUTD + t] = acc[r] + bl;
}

extern "C" void kernel_launch(void* const* d_in, const int* in_sizes, int n_in,
                              void* d_out, int out_size, void* d_ws, size_t ws_size,
                              hipStream_t stream) {
    const float* x     = (const float*)d_in[0];
    const int*   seg   = (const int*)d_in[1];
    const float* watl  = (const float*)d_in[2];
    const float* watr  = (const float*)d_in[3];
    const float* Wnode = (const float*)d_in[4];
    const float* Wih   = (const float*)d_in[5];
    const float* Whh   = (const float*)d_in[6];
    const float* bih   = (const float*)d_in[7];
    const float* bhh   = (const float*)d_in[8];
    const float* Wlin  = (const float*)d_in[9];
    const float* blin  = (const float*)d_in[10];
    float* out = (float*)d_out;

    char* ws = (char*)d_ws;
    size_t off = 0;
    auto alloc = [&](size_t bytes) -> void* {
        void* p = ws + off;
        off += bytes;
        off = (off + 255) & ~(size_t)255;
        return p;
    };
    float*          left    = (float*)          alloc((size_t)N_NODES * sizeof(float));
    float*          hcur    = (float*)          alloc((size_t)NGRAPH * DIM * sizeof(float));
    unsigned short* hcurbf  = (unsigned short*) alloc((size_t)NGRAPH * DIM * 2);
    unsigned short* hgbf    = (unsigned short*) alloc((size_t)NGRAPH * DIM * 2);
    unsigned short* swbf    = (unsigned short*) alloc((size_t)NGRAPH * DIM * 2);
    unsigned short* gib     = (unsigned short*) alloc((size_t)NGRAPH * HID3 * 2);
    unsigned short* ghb     = (unsigned short*) alloc((size_t)NGRAPH * HID3 * 2);
    unsigned short* WnT     = (unsigned short*) alloc((size_t)DIM * DIM * 2);
    unsigned short* Wihb    = (unsigned short*) alloc((size_t)HID3 * DIM * 2);
    unsigned short* Whhb    = (unsigned short*) alloc((size_t)HID3 * DIM * 2);
    int*            starts  = (int*)            alloc((NGRAPH + 1) * sizeof(int));
    unsigned char*  xq      = (unsigned char*)(ws + off);
    bool use_xq = (off + (size_t)N_NODES * DIM) <= ws_size;

    if (use_xq)
        k_init<true ><<<3840, 256, 0, stream>>>(x, seg, watl, Wih, Whh, Wnode,
                left, hcur, hcurbf, xq, Wihb, Whhb, WnT, starts);
    else
        k_init<false><<<3840, 256, 0, stream>>>(x, seg, watl, Wih, Whh, Wnode,
                left, hcur, hcurbf, nullptr, Wihb, Whhb, WnT, starts);

    for (int ts = 0; ts < 2; ts++) {
        if (use_xq) {
            if (ts == 0)
                k_att<true , false><<<NGRAPH, 256, 0, stream>>>(x, xq, left, starts,
                        hcur, hcurbf, gib, ghb, bih, bhh, watr, swbf);
            else
                k_att<true , true ><<<NGRAPH, 256, 0, stream>>>(x, xq, left, starts,
                        hcur, hcurbf, gib, ghb, bih, bhh, watr, swbf);
        } else {
            if (ts == 0)
                k_att<false, false><<<NGRAPH, 256, 0, stream>>>(x, xq, left, starts,
                        hcur, hcurbf, gib, ghb, bih, bhh, watr, swbf);
            else
                k_att<false, true ><<<NGRAPH, 256, 0, stream>>>(x, xq, left, starts,
                        hcur, hcurbf, gib, ghb, bih, bhh, watr, swbf);
        }
        // A': hg = elu(sw @ WnT^T)  [16 x 4 blocks]
        k_gemm<<<dim3(NGRAPH / 128, DIM / 128, 1), 256, 0, stream>>>(
            swbf, WnT, hgbf, 1, DIM,
            nullptr, nullptr, nullptr, 0, 0);
        // C: z=0 -> gi = hg @ Wih^T, z=1 -> gh = h @ Whh^T  [16 x 12 x 2 blocks]
        k_gemm<<<dim3(NGRAPH / 128, HID3 / 128, 2), 256, 0, stream>>>(
            hgbf, Wihb, gib, 2, HID3,
            hcurbf, Whhb, ghb, 2, HID3);
    }
    k_fin<<<NGRAPH / 16, 128, 0, stream>>>(hcur, gib, ghb, bih, bhh, Wlin, blin, out);
}

// Round 16
// 292.841 us; speedup vs baseline: 1.4181x; 1.1466x over previous
//
#include <hip/hip_runtime.h>
#include <hip/hip_bf16.h>
#include <cstdint>
#include <cstddef>

#define N_NODES 262144
#define NGRAPH  2048
#define DIM     512
#define HID3    1536
#define OUTD    128

typedef __attribute__((ext_vector_type(8))) short  short8;
typedef __attribute__((ext_vector_type(4))) float  floatx4;
typedef __attribute__((ext_vector_type(2))) float  floatx2;

__device__ inline unsigned short f2bf(float f) {
    union { float f; uint32_t u; } v; v.f = f;
    uint32_t u = v.u;
    return (unsigned short)((u + 0x7fffu + ((u >> 16) & 1u)) >> 16);
}
__device__ inline float bf2f(unsigned short h) {
    union { uint32_t u; float f; } v; v.u = ((uint32_t)h) << 16; return v.f;
}

__device__ __forceinline__ void gload_lds16(const void* g, void* l) {
    __builtin_amdgcn_global_load_lds((const __attribute__((address_space(1))) void*)g,
                                     (__attribute__((address_space(3))) void*)l, 16, 0, 0);
}

__device__ __forceinline__ int lbound(const int* __restrict__ seg, int b) {
    int lo = 0, hi = N_NODES;
    while (lo < hi) { int mid = (lo + hi) >> 1; if (seg[mid] < b) lo = mid + 1; else hi = mid; }
    return lo;
}

// ============ K1: init (sum-pool h0, left_att, x->fp8, starts) + weight prep ============
// nt-loads on x RESTORED (R15 A/B: removing them cost +43 us — they protect xq/left L3 residency).
template<bool WRITE_XQ>
__global__ __launch_bounds__(256) void k_init(const float* __restrict__ x,
        const int* __restrict__ seg, const float* __restrict__ watl,
        const float* __restrict__ Wih, const float* __restrict__ Whh,
        const float* __restrict__ Wnode,
        float* __restrict__ left_att, float* __restrict__ hcur,
        unsigned short* __restrict__ hcur_bf, unsigned char* __restrict__ xq,
        unsigned short* __restrict__ Wihb, unsigned short* __restrict__ Whhb,
        unsigned short* __restrict__ WnT, int* __restrict__ starts) {
    int t = threadIdx.x;
    int bid = blockIdx.x;

    if (bid >= 3584) {            // ---- WnT transpose ----
        __shared__ float tile[32][33];
        int idx = bid - 3584;
        int bx = idx >> 4, by = idx & 15;
        int tx = t & 31, ty = t >> 5;
        #pragma unroll
        for (int r = 0; r < 32; r += 8)
            tile[ty + r][tx] = Wnode[(size_t)(bx * 32 + ty + r) * DIM + by * 32 + tx];
        __syncthreads();
        #pragma unroll
        for (int r = 0; r < 32; r += 8)
            WnT[(size_t)(by * 32 + ty + r) * DIM + bx * 32 + tx] = f2bf(tile[tx][ty + r]);
        return;
    }
    if (bid >= 2048) {            // ---- Wih/Whh converts ----
        int isW2 = bid >= 2816;
        int i4 = (bid - (isW2 ? 2816 : 2048)) * 256 + t;
        const float* src = isW2 ? Whh : Wih;
        unsigned short* dst = isW2 ? Whhb : Wihb;
        floatx4 a = *reinterpret_cast<const floatx4*>(src + (size_t)i4 * 4);
        ushort4 o;
        o.x = f2bf(a[0]); o.y = f2bf(a[1]); o.z = f2bf(a[2]); o.w = f2bf(a[3]);
        *reinterpret_cast<ushort4*>(dst + (size_t)i4 * 4) = o;
        return;
    }

    // ---- per-graph init ----
    __shared__ float wl[DIM];
    __shared__ float red[4 * DIM];
    int b = bid;
    wl[t] = watl[t]; wl[t + 256] = watl[t + 256];
    int s = lbound(seg, b), e = lbound(seg, b + 1);
    if (t == 0) {
        starts[b] = s;
        if (b == NGRAPH - 1) starts[NGRAPH] = e;
    }
    __syncthreads();
    int w = t >> 6, lane = t & 63;
    int f0 = lane * 4;
    float acc[8] = {0.f,0.f,0.f,0.f,0.f,0.f,0.f,0.f};

    auto proc = [&](int i, floatx4 v0, floatx4 v1) {
        acc[0] += v0[0]; acc[1] += v0[1]; acc[2] += v0[2]; acc[3] += v0[3];
        acc[4] += v1[0]; acc[5] += v1[1]; acc[6] += v1[2]; acc[7] += v1[3];
        float dot = v0[0]*wl[f0] + v0[1]*wl[f0+1] + v0[2]*wl[f0+2] + v0[3]*wl[f0+3]
                  + v1[0]*wl[256+f0] + v1[1]*wl[256+f0+1] + v1[2]*wl[256+f0+2] + v1[3]*wl[256+f0+3];
        #pragma unroll
        for (int off = 32; off > 0; off >>= 1) dot += __shfl_xor(dot, off);
        if (lane == 0) left_att[i] = dot;
        if constexpr (WRITE_XQ) {
            unsigned int q0 = (unsigned int)__builtin_amdgcn_cvt_pk_fp8_f32(v0[0], v0[1], 0, false);
            q0 = (unsigned int)__builtin_amdgcn_cvt_pk_fp8_f32(v0[2], v0[3], (int)q0, true);
            unsigned int q1 = (unsigned int)__builtin_amdgcn_cvt_pk_fp8_f32(v1[0], v1[1], 0, false);
            q1 = (unsigned int)__builtin_amdgcn_cvt_pk_fp8_f32(v1[2], v1[3], (int)q1, true);
            *reinterpret_cast<unsigned int*>(xq + (size_t)i * DIM + f0) = q0;
            *reinterpret_cast<unsigned int*>(xq + (size_t)i * DIM + 256 + f0) = q1;
        }
    };

    auto ld = [&](int i, int half) -> floatx4 {
        return __builtin_nontemporal_load(
            reinterpret_cast<const floatx4*>(x + (size_t)i * DIM + half * 256 + f0));
    };

    int i = s + w;
    for (; i + 12 < e; i += 16) {
        floatx4 a0 = ld(i, 0),      a1 = ld(i, 1);
        floatx4 b0 = ld(i + 4, 0),  b1 = ld(i + 4, 1);
        floatx4 c0 = ld(i + 8, 0),  c1 = ld(i + 8, 1);
        floatx4 d0 = ld(i + 12, 0), d1 = ld(i + 12, 1);
        proc(i, a0, a1);
        proc(i + 4, b0, b1);
        proc(i + 8, c0, c1);
        proc(i + 12, d0, d1);
    }
    for (; i < e; i += 4) {
        floatx4 a0 = ld(i, 0), a1 = ld(i, 1);
        proc(i, a0, a1);
    }

    #pragma unroll
    for (int j = 0; j < 4; j++) {
        red[w * DIM + f0 + j]       = acc[j];
        red[w * DIM + 256 + f0 + j] = acc[4 + j];
    }
    __syncthreads();
    float s0 = red[t]       + red[DIM + t]       + red[2*DIM + t]       + red[3*DIM + t];
    float s1 = red[256 + t] + red[DIM + 256 + t] + red[2*DIM + 256 + t] + red[3*DIM + 256 + t];
    hcur[(size_t)b * DIM + t] = s0;
    hcur[(size_t)b * DIM + 256 + t] = s1;
    hcur_bf[(size_t)b * DIM + t] = f2bf(s0);
    hcur_bf[(size_t)b * DIM + 256 + t] = f2bf(s1);
}

// ============ K2: attention (+ optional fused GRU gate prologue, bf16 gi/gh) ============
template<bool XQ, bool FUSE_GATE>
__global__ __launch_bounds__(256) void k_att(const float* __restrict__ x,
        const unsigned char* __restrict__ xq, const float* __restrict__ left,
        const int* __restrict__ starts, float* __restrict__ hcur,
        unsigned short* __restrict__ hcurbf,
        const unsigned short* __restrict__ gib, const unsigned short* __restrict__ ghb,
        const float* __restrict__ bih, const float* __restrict__ bhh,
        const float* __restrict__ watr, unsigned short* __restrict__ swbf) {
    __shared__ float red[4 * DIM];
    __shared__ float rsh[4], rsm[4], rscal[4];
    int b = blockIdx.x, t = threadIdx.x;
    int w = t >> 6, lane = t & 63;

    float p;
    if constexpr (FUSE_GATE) {
        size_t gb = (size_t)b * HID3;
        float o01[2];
        #pragma unroll
        for (int half = 0; half < 2; ++half) {
            int j = t + half * 256;
            float gir = bf2f(gib[gb + j])        + bih[j];
            float giz = bf2f(gib[gb + 512 + j])  + bih[512 + j];
            float gin = bf2f(gib[gb + 1024 + j]) + bih[1024 + j];
            float ghr = bf2f(ghb[gb + j])        + bhh[j];
            float ghz = bf2f(ghb[gb + 512 + j])  + bhh[512 + j];
            float ghn = bf2f(ghb[gb + 1024 + j]) + bhh[1024 + j];
            float rg = 1.0f / (1.0f + __expf(-(gir + ghr)));
            float zg = 1.0f / (1.0f + __expf(-(giz + ghz)));
            float nn = tanhf(gin + rg * ghn);
            float hp = hcur[(size_t)b * DIM + j];
            float nh = (1.0f - zg) * nn + zg * hp;
            float o = nh / (1.0f + __expf(-nh));
            hcur[(size_t)b * DIM + j] = o;
            hcurbf[(size_t)b * DIM + j] = f2bf(o);
            o01[half] = o;
        }
        p = o01[0] * watr[t] + o01[1] * watr[t + 256];
    } else {
        p = hcur[(size_t)b * DIM + t] * watr[t] + hcur[(size_t)b * DIM + 256 + t] * watr[256 + t];
    }
    #pragma unroll
    for (int off = 32; off > 0; off >>= 1) p += __shfl_xor(p, off);
    if (lane == 0) rsh[w] = p;
    int s = starts[b], e = starts[b + 1];
    __syncthreads();
    float ra = rsh[0] + rsh[1] + rsh[2] + rsh[3];

    float m = -1e30f;
    for (int i = s + t; i < e; i += 256) {
        float a = left[i] + ra; a = a >= 0.f ? a : 0.01f * a;
        m = fmaxf(m, a);
    }
    #pragma unroll
    for (int off = 32; off > 0; off >>= 1) m = fmaxf(m, __shfl_xor(m, off));
    if (lane == 0) rsm[w] = m;
    __syncthreads();
    m = fmaxf(fmaxf(rsm[0], rsm[1]), fmaxf(rsm[2], rsm[3]));

    float esum = 0.f;
    if constexpr (XQ) {
        int h  = lane >> 5;
        int fl = (lane & 31) * 16;
        float acc[16];
        #pragma unroll
        for (int j = 0; j < 16; j++) acc[j] = 0.f;
        const unsigned char* xrow = xq + fl;

        auto rowcalc = [&](uint4 q, float lv) {
            float a = lv + ra; a = a >= 0.f ? a : 0.01f * a;
            float e0 = __expf(a - m);
            esum += e0;
            floatx2 p0 = __builtin_amdgcn_cvt_pk_f32_fp8((int)q.x, false);
            floatx2 p1 = __builtin_amdgcn_cvt_pk_f32_fp8((int)q.x, true);
            floatx2 p2 = __builtin_amdgcn_cvt_pk_f32_fp8((int)q.y, false);
            floatx2 p3 = __builtin_amdgcn_cvt_pk_f32_fp8((int)q.y, true);
            floatx2 p4 = __builtin_amdgcn_cvt_pk_f32_fp8((int)q.z, false);
            floatx2 p5 = __builtin_amdgcn_cvt_pk_f32_fp8((int)q.z, true);
            floatx2 p6 = __builtin_amdgcn_cvt_pk_f32_fp8((int)q.w, false);
            floatx2 p7 = __builtin_amdgcn_cvt_pk_f32_fp8((int)q.w, true);
            acc[0]  += e0 * p0[0]; acc[1]  += e0 * p0[1];
            acc[2]  += e0 * p1[0]; acc[3]  += e0 * p1[1];
            acc[4]  += e0 * p2[0]; acc[5]  += e0 * p2[1];
            acc[6]  += e0 * p3[0]; acc[7]  += e0 * p3[1];
            acc[8]  += e0 * p4[0]; acc[9]  += e0 * p4[1];
            acc[10] += e0 * p5[0]; acc[11] += e0 * p5[1];
            acc[12] += e0 * p6[0]; acc[13] += e0 * p6[1];
            acc[14] += e0 * p7[0]; acc[15] += e0 * p7[1];
        };

        int base = s + 2 * w;
        for (; base + 26 <= e; base += 32) {
            int r0 = base + h, r1 = base + 8 + h, r2 = base + 16 + h, r3 = base + 24 + h;
            uint4 q0 = *reinterpret_cast<const uint4*>(xrow + (size_t)r0 * DIM);
            uint4 q1 = *reinterpret_cast<const uint4*>(xrow + (size_t)r1 * DIM);
            uint4 q2 = *reinterpret_cast<const uint4*>(xrow + (size_t)r2 * DIM);
            uint4 q3 = *reinterpret_cast<const uint4*>(xrow + (size_t)r3 * DIM);
            float l0 = left[r0], l1 = left[r1], l2 = left[r2], l3 = left[r3];
            rowcalc(q0, l0); rowcalc(q1, l1); rowcalc(q2, l2); rowcalc(q3, l3);
        }
        for (; base + 10 <= e; base += 16) {
            int r0 = base + h, r1 = base + 8 + h;
            uint4 q0 = *reinterpret_cast<const uint4*>(xrow + (size_t)r0 * DIM);
            uint4 q1 = *reinterpret_cast<const uint4*>(xrow + (size_t)r1 * DIM);
            float l0 = left[r0], l1 = left[r1];
            rowcalc(q0, l0); rowcalc(q1, l1);
        }
        for (; base < e; base += 8) {
            int r = base + h;
            if (r < e) {
                uint4 q = *reinterpret_cast<const uint4*>(xrow + (size_t)r * DIM);
                rowcalc(q, left[r]);
            }
        }
        #pragma unroll
        for (int j = 0; j < 16; j++) acc[j] += __shfl_xor(acc[j], 32);
        if (lane < 32) {
            #pragma unroll
            for (int j = 0; j < 16; j++) red[w * DIM + fl + j] = acc[j];
        }
    } else {
        int f0 = lane * 4;
        float acc[8] = {0.f,0.f,0.f,0.f,0.f,0.f,0.f,0.f};
        for (int i = s + w; i < e; i += 4) {
            float a0 = left[i] + ra; a0 = a0 >= 0.f ? a0 : 0.01f * a0;
            float e0 = __expf(a0 - m);
            esum += e0 * 32.0f;
            float4 v0 = *reinterpret_cast<const float4*>(x + (size_t)i * DIM + f0);
            float4 v1 = *reinterpret_cast<const float4*>(x + (size_t)i * DIM + 256 + f0);
            acc[0] += e0 * v0.x; acc[1] += e0 * v0.y; acc[2] += e0 * v0.z; acc[3] += e0 * v0.w;
            acc[4] += e0 * v1.x; acc[5] += e0 * v1.y; acc[6] += e0 * v1.z; acc[7] += e0 * v1.w;
        }
        #pragma unroll
        for (int j = 0; j < 4; j++) {
            red[w * DIM + f0 + j]       = acc[j];
            red[w * DIM + 256 + f0 + j] = acc[4 + j];
        }
    }
    #pragma unroll
    for (int off = 32; off > 0; off >>= 1) esum += __shfl_xor(esum, off);
    if (lane == 0) rscal[w] = esum;
    __syncthreads();
    float tot = (rscal[0] + rscal[1] + rscal[2] + rscal[3]) * (1.0f / 32.0f);
    float inv = tot > 0.f ? 1.0f / tot : 0.0f;
    float s0 = (red[t]       + red[DIM + t]       + red[2*DIM + t]       + red[3*DIM + t])       * inv;
    float s1 = (red[256 + t] + red[DIM + 256 + t] + red[2*DIM + 256 + t] + red[3*DIM + 256 + t]) * inv;
    swbf[(size_t)b * DIM + t] = f2bf(s0);
    swbf[(size_t)b * DIM + 256 + t] = f2bf(s1);
}

// ============ K3: bf16 MFMA GEMM, 2-phase pipeline, dual-problem z-select ============
// mode: 1 = elu -> bf16, 2 = plain bf16
__global__ __launch_bounds__(256, 2) void k_gemm(const unsigned short* __restrict__ A0,
        const unsigned short* __restrict__ Wt0, unsigned short* __restrict__ C0,
        int mode0, int Ncols0,
        const unsigned short* __restrict__ A1, const unsigned short* __restrict__ Wt1,
        unsigned short* __restrict__ C1, int mode1, int Ncols1) {
    const int z = blockIdx.z;
    const unsigned short* A  = z ? A1  : A0;
    const unsigned short* Wt = z ? Wt1 : Wt0;
    unsigned short* C = z ? C1 : C0;
    const int mode  = z ? mode1 : mode0;
    const int Ncols = z ? Ncols1 : Ncols0;

    __shared__ __align__(16) unsigned short lA[2][128 * 64];
    __shared__ __align__(16) unsigned short lW[2][128 * 64];

    int t = threadIdx.x;
    int w = t >> 6, lane = t & 63;
    int wr = w >> 1, wc = w & 1;
    int mbase = blockIdx.x * 128;
    int nbase = blockIdx.y * 128;
    int fr = lane & 15, hi = lane >> 4;
    int swz_r = (fr & 7) << 4;

    int rbase = t >> 3;
    int cole = ((((t & 7) * 16) ^ ((rbase & 7) << 4)) >> 1);
    int ldsoff = t * 16;

    floatx4 acc[4][4];
    #pragma unroll
    for (int m = 0; m < 4; m++)
        #pragma unroll
        for (int n = 0; n < 4; n++) {
            acc[m][n][0] = 0.f; acc[m][n][1] = 0.f; acc[m][n][2] = 0.f; acc[m][n][3] = 0.f;
        }

    const unsigned short* gA = A  + (size_t)(mbase + rbase) * DIM + cole;
    const unsigned short* gW = Wt + (size_t)(nbase + rbase) * DIM + cole;

    auto stage = [&](int kk, int buf) {
        #pragma unroll
        for (int c = 0; c < 4; ++c) {
            gload_lds16(gA + (size_t)(c * 32) * DIM + kk, (char*)&lA[buf][0] + c * 4096 + ldsoff);
            gload_lds16(gW + (size_t)(c * 32) * DIM + kk, (char*)&lW[buf][0] + c * 4096 + ldsoff);
        }
    };

    stage(0, 0);
    __syncthreads();
    int cur = 0;
    for (int it = 0; it < 8; ++it) {
        if (it < 7) stage((it + 1) * 64, cur ^ 1);
        #pragma unroll
        for (int ks = 0; ks < 2; ++ks) {
            short8 af[4], bf[4];
            int bc = (ks * 64 + hi * 16) ^ swz_r;
            #pragma unroll
            for (int m = 0; m < 4; ++m) {
                int row = wr * 64 + m * 16 + fr;
                af[m] = *reinterpret_cast<const short8*>(&lA[cur][(row * 128 + bc) >> 1]);
            }
            #pragma unroll
            for (int n = 0; n < 4; ++n) {
                int row = wc * 64 + n * 16 + fr;
                bf[n] = *reinterpret_cast<const short8*>(&lW[cur][(row * 128 + bc) >> 1]);
            }
            #pragma unroll
            for (int m = 0; m < 4; ++m)
                #pragma unroll
                for (int n = 0; n < 4; ++n)
                    acc[m][n] = __builtin_amdgcn_mfma_f32_16x16x32_bf16(af[m], bf[n], acc[m][n], 0, 0, 0);
        }
        if (it < 7) __syncthreads();
        cur ^= 1;
    }

    int rq = hi * 4;
    #pragma unroll
    for (int m = 0; m < 4; m++) {
        #pragma unroll
        for (int n = 0; n < 4; n++) {
            int col = nbase + wc * 64 + n * 16 + fr;
            #pragma unroll
            for (int r = 0; r < 4; r++) {
                int row = mbase + wr * 64 + m * 16 + rq + r;
                float v = acc[m][n][r];
                if (mode == 1) v = v > 0.f ? v : (__expf(v) - 1.0f);
                C[(size_t)row * Ncols + col] = f2bf(v);
            }
        }
    }
}

// ============ K4: final linear with fused GRU gate (ts1, bf16 gi/gh) ============
__global__ __launch_bounds__(128) void k_fin(const float* __restrict__ hcur,
        const unsigned short* __restrict__ gib, const unsigned short* __restrict__ ghb,
        const float* __restrict__ bih, const float* __restrict__ bhh,
        const float* __restrict__ Wlin, const float* __restrict__ blin,
        float* __restrict__ out) {
    __shared__ float rows[16 * DIM];
    int t = threadIdx.x;
    int b0 = blockIdx.x * 16;
    for (int k = 0; k < 16; ++k) {
        int i4 = t + k * 128;
        int bl = i4 >> 7;
        int j  = (i4 & 127) << 2;
        size_t gb = (size_t)(b0 + bl) * HID3;
        ushort4 gir4 = *reinterpret_cast<const ushort4*>(gib + gb + j);
        ushort4 giz4 = *reinterpret_cast<const ushort4*>(gib + gb + 512 + j);
        ushort4 gin4 = *reinterpret_cast<const ushort4*>(gib + gb + 1024 + j);
        ushort4 ghr4 = *reinterpret_cast<const ushort4*>(ghb + gb + j);
        ushort4 ghz4 = *reinterpret_cast<const ushort4*>(ghb + gb + 512 + j);
        ushort4 ghn4 = *reinterpret_cast<const ushort4*>(ghb + gb + 1024 + j);
        floatx4 bir = *reinterpret_cast<const floatx4*>(bih + j);
        floatx4 biz = *reinterpret_cast<const floatx4*>(bih + 512 + j);
        floatx4 bin = *reinterpret_cast<const floatx4*>(bih + 1024 + j);
        floatx4 bhr = *reinterpret_cast<const floatx4*>(bhh + j);
        floatx4 bhz = *reinterpret_cast<const floatx4*>(bhh + 512 + j);
        floatx4 bhn = *reinterpret_cast<const floatx4*>(bhh + 1024 + j);
        floatx4 hp  = *reinterpret_cast<const floatx4*>(hcur + (size_t)(b0 + bl) * DIM + j);
        floatx4 ov;
        const unsigned short* girp = &gir4.x;
        const unsigned short* gizp = &giz4.x;
        const unsigned short* ginp = &gin4.x;
        const unsigned short* ghrp = &ghr4.x;
        const unsigned short* ghzp = &ghz4.x;
        const unsigned short* ghnp = &ghn4.x;
        #pragma unroll
        for (int r = 0; r < 4; r++) {
            float rg = 1.0f / (1.0f + __expf(-(bf2f(girp[r]) + bir[r] + bf2f(ghrp[r]) + bhr[r])));
            float zg = 1.0f / (1.0f + __expf(-(bf2f(gizp[r]) + biz[r] + bf2f(ghzp[r]) + bhz[r])));
            float nn = tanhf(bf2f(ginp[r]) + bin[r] + rg * (bf2f(ghnp[r]) + bhn[r]));
            float nh = (1.0f - zg) * nn + zg * hp[r];
            ov[r] = nh / (1.0f + __expf(-nh));
        }
        *reinterpret_cast<floatx4*>(rows + (size_t)i4 * 4) = ov;
    }
    __syncthreads();
    float acc[16];
    #pragma unroll
    for (int r = 0; r < 16; r++) acc[r] = 0.f;
    #pragma unroll 4
    for (int k = 0; k < DIM; k++) {
        float wv = Wlin[k * OUTD + t];
        #pragma unroll
        for (int r = 0; r < 16; r++) acc[r] += rows[r * DIM + k] * wv;
    }
    float bl = blin[t];
    #pragma unroll
    for (int r = 0; r < 16; r++) out[(size_t)(b0 + r) * OUTD + t] = acc[r] + bl;
}

extern "C" void kernel_launch(void* const* d_in, const int* in_sizes, int n_in,
                              void* d_out, int out_size, void* d_ws, size_t ws_size,
                              hipStream_t stream) {
    const float* x     = (const float*)d_in[0];
    const int*   seg   = (const int*)d_in[1];
    const float* watl  = (const float*)d_in[2];
    const float* watr  = (const float*)d_in[3];
    const float* Wnode = (const float*)d_in[4];
    const float* Wih   = (const float*)d_in[5];
    const float* Whh   = (const float*)d_in[6];
    const float* bih   = (const float*)d_in[7];
    const float* bhh   = (const float*)d_in[8];
    const float* Wlin  = (const float*)d_in[9];
    const float* blin  = (const float*)d_in[10];
    float* out = (float*)d_out;

    char* ws = (char*)d_ws;
    size_t off = 0;
    auto alloc = [&](size_t bytes) -> void* {
        void* p = ws + off;
        off += bytes;
        off = (off + 255) & ~(size_t)255;
        return p;
    };
    float*          left    = (float*)          alloc((size_t)N_NODES * sizeof(float));
    float*          hcur    = (float*)          alloc((size_t)NGRAPH * DIM * sizeof(float));
    unsigned short* hcurbf  = (unsigned short*) alloc((size_t)NGRAPH * DIM * 2);
    unsigned short* hgbf    = (unsigned short*) alloc((size_t)NGRAPH * DIM * 2);
    unsigned short* swbf    = (unsigned short*) alloc((size_t)NGRAPH * DIM * 2);
    unsigned short* gib     = (unsigned short*) alloc((size_t)NGRAPH * HID3 * 2);
    unsigned short* ghb     = (unsigned short*) alloc((size_t)NGRAPH * HID3 * 2);
    unsigned short* WnT     = (unsigned short*) alloc((size_t)DIM * DIM * 2);
    unsigned short* Wihb    = (unsigned short*) alloc((size_t)HID3 * DIM * 2);
    unsigned short* Whhb    = (unsigned short*) alloc((size_t)HID3 * DIM * 2);
    int*            starts  = (int*)            alloc((NGRAPH + 1) * sizeof(int));
    unsigned char*  xq      = (unsigned char*)(ws + off);
    bool use_xq = (off + (size_t)N_NODES * DIM) <= ws_size;

    if (use_xq)
        k_init<true ><<<3840, 256, 0, stream>>>(x, seg, watl, Wih, Whh, Wnode,
                left, hcur, hcurbf, xq, Wihb, Whhb, WnT, starts);
    else
        k_init<false><<<3840, 256, 0, stream>>>(x, seg, watl, Wih, Whh, Wnode,
                left, hcur, hcurbf, nullptr, Wihb, Whhb, WnT, starts);

    for (int ts = 0; ts < 2; ts++) {
        if (use_xq) {
            if (ts == 0)
                k_att<true , false><<<NGRAPH, 256, 0, stream>>>(x, xq, left, starts,
                        hcur, hcurbf, gib, ghb, bih, bhh, watr, swbf);
            else
                k_att<true , true ><<<NGRAPH, 256, 0, stream>>>(x, xq, left, starts,
                        hcur, hcurbf, gib, ghb, bih, bhh, watr, swbf);
        } else {
            if (ts == 0)
                k_att<false, false><<<NGRAPH, 256, 0, stream>>>(x, xq, left, starts,
                        hcur, hcurbf, gib, ghb, bih, bhh, watr, swbf);
            else
                k_att<false, true ><<<NGRAPH, 256, 0, stream>>>(x, xq, left, starts,
                        hcur, hcurbf, gib, ghb, bih, bhh, watr, swbf);
        }
        // A': hg = elu(sw @ WnT^T)  [16 x 4 blocks]
        k_gemm<<<dim3(NGRAPH / 128, DIM / 128, 1), 256, 0, stream>>>(
            swbf, WnT, hgbf, 1, DIM,
            nullptr, nullptr, nullptr, 0, 0);
        // C: z=0 -> gi = hg @ Wih^T, z=1 -> gh = h @ Whh^T  [16 x 12 x 2 blocks]
        k_gemm<<<dim3(NGRAPH / 128, HID3 / 128, 2), 256, 0, stream>>>(
            hgbf, Wihb, gib, 2, HID3,
            hcurbf, Whhb, ghb, 2, HID3);
    }
    k_fin<<<NGRAPH / 16, 128, 0, stream>>>(hcur, gib, ghb, bih, bhh, Wlin, blin, out);
}